// Round 3
// baseline (1258.895 us; speedup 1.0000x reference)
//
#include <hip/hip_runtime.h>

// Neighbor search: M=N=12288, DIM=3.
// d_out layout (float32, flat, return order):
//   [0 .. M]                row_splits (M+1 counts-prefix as floats)
//   [M+1 .. M+1+M*N)        mask (0.0 / 1.0)
//   [M+1+M*N .. +2*M*N)     weights (d2 if mask else 0)
//
// R2 post-mortem: LDS gather fix bought ~nothing -> limiter is the store
// path + per-element overhead. R3: process rows in float4 quads whose wave
// store spans are fully 64B-line-covered (row flat base == 1 mod 16 floats,
// so bulk starts at in-tile element 15), LDS tile shifted +3 words so each
// quad's 12 floats come from 3x ds_read_b128 (conflict-free: lane starts
// 12c mod 32). 4x fewer store/LDS/addr instructions per element.
//
// Numerics (matches R1/R2, absmax 256 deterministic, threshold 7004):
//   sq = (x*x + y*y) + z*z               (each op rounded)
//   dot = fma(q2,d2, fma(q1,d1, q0*d0))  (sgemm ascending-k chain)
//   v = fma(-2, dot, sq_q+sq_d)          (== (sq_q+sq_d) - 2*dot exactly)
//   v = max(v,0); mask = v <= r*r

#define TILE 1024  // 1024*3+4 floats = 12.3 KB LDS -> 8 blocks/CU (wave-capped)

__global__ __launch_bounds__(256) void nbr_kernel(
    const float* __restrict__ data,
    const float* __restrict__ queries,
    const float* __restrict__ radius_p,
    float* __restrict__ out,
    int* __restrict__ counts,
    int N, long long mask_off, long long w_off)
{
    __shared__ __align__(16) float tile[TILE * 3 + 4];  // +3-word shift, rounded

    const int m = blockIdx.x;
    const int tid = threadIdx.x;

    const float r = radius_p[0];
    const float r2 = __fmul_rn(r, r);
    const float q0 = queries[3 * m + 0];
    const float q1 = queries[3 * m + 1];
    const float q2 = queries[3 * m + 2];
    const float sq_q = __fadd_rn(
        __fadd_rn(__fmul_rn(q0, q0), __fmul_rn(q1, q1)), __fmul_rn(q2, q2));

    float* mask_row = out + mask_off + (long long)m * N;
    float* w_row    = out + w_off    + (long long)m * N;

    int cnt = 0;

    auto compute = [&](float d0, float d1, float d2e, float& mv, float& wv) -> int {
        const float sq_d = __fadd_rn(
            __fadd_rn(__fmul_rn(d0, d0), __fmul_rn(d1, d1)), __fmul_rn(d2e, d2e));
        const float dot = __fmaf_rn(q2, d2e, __fmaf_rn(q1, d1, __fmul_rn(q0, d0)));
        const float s = __fadd_rn(sq_q, sq_d);
        float v = __fmaf_rn(-2.0f, dot, s);  // == __fsub_rn(s, __fmul_rn(2,dot))
        v = fmaxf(v, 0.0f);
        const bool in = (v <= r2);
        mv = in ? 1.0f : 0.0f;
        wv = in ? v : 0.0f;
        return in ? 1 : 0;
    };

    constexpr int NQ = (TILE - 16) / 4;  // 252 quads per tile

    for (int tb = 0; tb < N; tb += TILE) {
        __syncthreads();  // previous tile's readers done before overwrite
        // Stage data[3*tb .. 3*tb+3*TILE) into tile[3 ..], coalesced float4
        // global loads; LDS written +3 words so quad reads are b128-aligned.
        {
            const float4* src = reinterpret_cast<const float4*>(data + 3LL * tb);
            #pragma unroll
            for (int k = 0; k < 3 * TILE / 4 / 256; ++k) {  // 3 iters
                const int f = k * 256 + tid;
                const float4 v = src[f];
                const int w = 4 * f + 3;
                tile[w + 0] = v.x;
                tile[w + 1] = v.y;
                tile[w + 2] = v.z;
                tile[w + 3] = v.w;
            }
        }
        __syncthreads();

        // Head (n=0..14) + tail (n=TILE-1): 16 scalar elements per tile so
        // the quad bulk's wave spans are 64B-line aligned.
        if (tid < 16) {
            const int n = (tid < 15) ? tid : (TILE - 1);
            float mv, wv;
            cnt += compute(tile[3 * n + 3], tile[3 * n + 4], tile[3 * n + 5], mv, wv);
            mask_row[tb + n] = mv;
            w_row[tb + n] = wv;
        }

        // Bulk: quad c covers elements n = 15 + 4c .. 18 + 4c.
        // LDS words 48+12c .. 59+12c: three aligned b128 reads.
        if (tid < NQ) {
            const int c = tid;
            const float4 A = *reinterpret_cast<const float4*>(&tile[48 + 12 * c]);
            const float4 B = *reinterpret_cast<const float4*>(&tile[52 + 12 * c]);
            const float4 C = *reinterpret_cast<const float4*>(&tile[56 + 12 * c]);
            float4 mv, wv;
            cnt += compute(A.x, A.y, A.z, mv.x, wv.x);
            cnt += compute(A.w, B.x, B.y, mv.y, wv.y);
            cnt += compute(B.z, B.w, C.x, mv.z, wv.z);
            cnt += compute(C.y, C.z, C.w, mv.w, wv.w);
            const long long g = (long long)tb + 15 + 4 * c;  // flat off == 0 mod 16
            *reinterpret_cast<float4*>(mask_row + g) = mv;   // 64B lines fully covered
            *reinterpret_cast<float4*>(w_row + g) = wv;
        }
    }

    // Block count reduction: wave shuffle, then LDS across the 4 waves.
    for (int off = 32; off > 0; off >>= 1) cnt += __shfl_down(cnt, off);
    __shared__ int lds_cnt;
    if (tid == 0) lds_cnt = 0;
    __syncthreads();
    if ((tid & 63) == 0) atomicAdd(&lds_cnt, cnt);
    __syncthreads();
    if (tid == 0) counts[m] = lds_cnt;
}

// Generic fallback (shape assumptions not met): per-element, correct-first.
__global__ __launch_bounds__(256) void nbr_kernel_generic(
    const float* __restrict__ data,
    const float* __restrict__ queries,
    const float* __restrict__ radius_p,
    float* __restrict__ out,
    int* __restrict__ counts,
    int N, long long mask_off, long long w_off)
{
    const int m = blockIdx.x;
    const int tid = threadIdx.x;
    const float r = radius_p[0];
    const float r2 = __fmul_rn(r, r);
    const float q0 = queries[3 * m + 0], q1 = queries[3 * m + 1], q2 = queries[3 * m + 2];
    const float sq_q = __fadd_rn(
        __fadd_rn(__fmul_rn(q0, q0), __fmul_rn(q1, q1)), __fmul_rn(q2, q2));
    float* mask_row = out + mask_off + (long long)m * N;
    float* w_row    = out + w_off    + (long long)m * N;
    int cnt = 0;
    for (int n = tid; n < N; n += 256) {
        const float d0 = data[3 * n], d1 = data[3 * n + 1], d2e = data[3 * n + 2];
        const float sq_d = __fadd_rn(
            __fadd_rn(__fmul_rn(d0, d0), __fmul_rn(d1, d1)), __fmul_rn(d2e, d2e));
        const float dot = __fmaf_rn(q2, d2e, __fmaf_rn(q1, d1, __fmul_rn(q0, d0)));
        float v = __fmaf_rn(-2.0f, dot, __fadd_rn(sq_q, sq_d));
        v = fmaxf(v, 0.0f);
        const bool in = (v <= r2);
        mask_row[n] = in ? 1.0f : 0.0f;
        w_row[n] = in ? v : 0.0f;
        cnt += in ? 1 : 0;
    }
    for (int off = 32; off > 0; off >>= 1) cnt += __shfl_down(cnt, off);
    __shared__ int lds_cnt;
    if (tid == 0) lds_cnt = 0;
    __syncthreads();
    if ((tid & 63) == 0) atomicAdd(&lds_cnt, cnt);
    __syncthreads();
    if (tid == 0) counts[m] = lds_cnt;
}

// Single-block exclusive scan of counts[M] -> row_splits[M+1] (as floats).
__global__ __launch_bounds__(256) void scan_kernel(
    const int* __restrict__ counts, float* __restrict__ out, int M)
{
    __shared__ int sums[256];
    const int t = threadIdx.x;
    const int CH = (M + 255) / 256;  // 48 for M=12288
    const int base = t * CH;

    int local[64];  // CH <= 64 assumed
    int s = 0;
    for (int i = 0; i < CH; ++i) {
        const int v = (base + i < M) ? counts[base + i] : 0;
        local[i] = v;
        s += v;
    }
    sums[t] = s;
    __syncthreads();
    for (int off = 1; off < 256; off <<= 1) {
        const int v = (t >= off) ? sums[t - off] : 0;
        __syncthreads();
        sums[t] += v;
        __syncthreads();
    }
    int prefix = sums[t] - s;  // exclusive prefix of this thread's chunk
    for (int i = 0; i < CH; ++i) {
        if (base + i < M) out[base + i] = (float)prefix;
        prefix += local[i];
    }
    if (t == 255) out[M] = (float)prefix;  // total
}

extern "C" void kernel_launch(void* const* d_in, const int* in_sizes, int n_in,
                              void* d_out, int out_size, void* d_ws, size_t ws_size,
                              hipStream_t stream) {
    const float* data    = (const float*)d_in[0];
    const float* queries = (const float*)d_in[1];
    const float* radius  = (const float*)d_in[2];

    const int N = in_sizes[0] / 3;  // 12288
    const int M = in_sizes[1] / 3;  // 12288

    float* out = (float*)d_out;
    int* counts = (int*)d_ws;

    const long long mask_off = (long long)M + 1;
    const long long w_off = mask_off + (long long)M * N;

    // Fast path needs: rows tile-divisible and flat row base == 1 (mod 16).
    const bool fast = (N % TILE == 0) && (M % 16 == 0) && (N % 16 == 0);
    if (fast) {
        nbr_kernel<<<M, 256, 0, stream>>>(data, queries, radius, out, counts,
                                          N, mask_off, w_off);
    } else {
        nbr_kernel_generic<<<M, 256, 0, stream>>>(data, queries, radius, out,
                                                  counts, N, mask_off, w_off);
    }
    scan_kernel<<<1, 256, 0, stream>>>(counts, out, M);
}

// Round 4
// 1256.228 us; speedup vs baseline: 1.0021x; 1.0021x over previous
//
#include <hip/hip_runtime.h>

// Neighbor search: M=N=12288, DIM=3.
// d_out layout (float32, flat, return order):
//   [0 .. M]                row_splits (M+1 counts-prefix as floats)
//   [M+1 .. M+1+M*N)        mask (0.0 / 1.0)
//   [M+1+M*N .. +2*M*N)     weights (d2 if mask else 0)
//
// R1-R3 post-mortem: three disjoint kernel structures (global gathers /
// LDS / b128 + aligned float4 stores, 4x fewer instrs) all tie at ~480us
// kernel share vs a 192us store floor (harness fill proves 6.27 TB/s on
// this very buffer). Kernel is issue-insensitive -> memory-pattern bound.
// Theory: write-channel camping. Concurrent blocks write rows m*48KiB + d
// with d in lockstep; 48KiB stride is weakly whitened by the channel hash
// so the instantaneous footprint camps on a channel subset (~40% BW =
// 2.5/6.3 observed). The harness fill's grid-stride footprint is
// contiguous across blocks -> no camping -> 6.27 TB/s.
// R4 fix (single variable): rotate tile phase per block (start at tile
// m % 12, wrap) so concurrent blocks spread uniformly over 12 x 4KiB
// phases within their rows. Everything else identical to R3.
//
// Numerics (unchanged since R1, absmax 256, threshold 7004):
//   sq = (x*x + y*y) + z*z               (each op rounded)
//   dot = fma(q2,d2, fma(q1,d1, q0*d0))  (sgemm ascending-k chain)
//   v = fma(-2, dot, sq_q+sq_d)          (== (sq_q+sq_d) - 2*dot exactly)
//   v = max(v,0); mask = v <= r*r

#define TILE 1024  // 1024*3+4 floats = 12.3 KB LDS

__global__ __launch_bounds__(256) void nbr_kernel(
    const float* __restrict__ data,
    const float* __restrict__ queries,
    const float* __restrict__ radius_p,
    float* __restrict__ out,
    int* __restrict__ counts,
    int N, long long mask_off, long long w_off)
{
    __shared__ __align__(16) float tile[TILE * 3 + 4];  // +3-word shift, rounded

    const int m = blockIdx.x;
    const int tid = threadIdx.x;

    const float r = radius_p[0];
    const float r2 = __fmul_rn(r, r);
    const float q0 = queries[3 * m + 0];
    const float q1 = queries[3 * m + 1];
    const float q2 = queries[3 * m + 2];
    const float sq_q = __fadd_rn(
        __fadd_rn(__fmul_rn(q0, q0), __fmul_rn(q1, q1)), __fmul_rn(q2, q2));

    float* mask_row = out + mask_off + (long long)m * N;
    float* w_row    = out + w_off    + (long long)m * N;

    int cnt = 0;

    auto compute = [&](float d0, float d1, float d2e, float& mv, float& wv) -> int {
        const float sq_d = __fadd_rn(
            __fadd_rn(__fmul_rn(d0, d0), __fmul_rn(d1, d1)), __fmul_rn(d2e, d2e));
        const float dot = __fmaf_rn(q2, d2e, __fmaf_rn(q1, d1, __fmul_rn(q0, d0)));
        const float s = __fadd_rn(sq_q, sq_d);
        float v = __fmaf_rn(-2.0f, dot, s);  // == __fsub_rn(s, __fmul_rn(2,dot))
        v = fmaxf(v, 0.0f);
        const bool in = (v <= r2);
        mv = in ? 1.0f : 0.0f;
        wv = in ? v : 0.0f;
        return in ? 1 : 0;
    };

    constexpr int NQ = (TILE - 16) / 4;  // 252 quads per tile
    const int ntiles = N / TILE;         // 12

    // Phase rotation: block m starts at tile (m % ntiles) and wraps, so
    // concurrently-running blocks write decorrelated row offsets.
    for (int t = 0; t < ntiles; ++t) {
        int tt = t + (m % ntiles);
        if (tt >= ntiles) tt -= ntiles;
        const int tb = tt * TILE;

        __syncthreads();  // previous tile's readers done before overwrite
        // Stage data[3*tb .. 3*tb+3*TILE) into tile[3 ..], coalesced float4
        // global loads; LDS written +3 words so quad reads are b128-aligned.
        {
            const float4* src = reinterpret_cast<const float4*>(data + 3LL * tb);
            #pragma unroll
            for (int k = 0; k < 3 * TILE / 4 / 256; ++k) {  // 3 iters
                const int f = k * 256 + tid;
                const float4 v = src[f];
                const int w = 4 * f + 3;
                tile[w + 0] = v.x;
                tile[w + 1] = v.y;
                tile[w + 2] = v.z;
                tile[w + 3] = v.w;
            }
        }
        __syncthreads();

        // Head (n=0..14) + tail (n=TILE-1): 16 scalar elements per tile so
        // the quad bulk's wave spans are 64B-line aligned (row base == 1 mod 16,
        // tb == 0 mod 16 -> tb+15 == 0 mod 16 flat).
        if (tid < 16) {
            const int n = (tid < 15) ? tid : (TILE - 1);
            float mv, wv;
            cnt += compute(tile[3 * n + 3], tile[3 * n + 4], tile[3 * n + 5], mv, wv);
            mask_row[tb + n] = mv;
            w_row[tb + n] = wv;
        }

        // Bulk: quad c covers elements n = 15 + 4c .. 18 + 4c.
        // LDS words 48+12c .. 59+12c: three aligned b128 reads.
        if (tid < NQ) {
            const int c = tid;
            const float4 A = *reinterpret_cast<const float4*>(&tile[48 + 12 * c]);
            const float4 B = *reinterpret_cast<const float4*>(&tile[52 + 12 * c]);
            const float4 C = *reinterpret_cast<const float4*>(&tile[56 + 12 * c]);
            float4 mv, wv;
            cnt += compute(A.x, A.y, A.z, mv.x, wv.x);
            cnt += compute(A.w, B.x, B.y, mv.y, wv.y);
            cnt += compute(B.z, B.w, C.x, mv.z, wv.z);
            cnt += compute(C.y, C.z, C.w, mv.w, wv.w);
            const long long g = (long long)tb + 15 + 4 * c;  // flat off == 0 mod 16
            *reinterpret_cast<float4*>(mask_row + g) = mv;   // 64B lines fully covered
            *reinterpret_cast<float4*>(w_row + g) = wv;
        }
    }

    // Block count reduction: wave shuffle, then LDS across the 4 waves.
    for (int off = 32; off > 0; off >>= 1) cnt += __shfl_down(cnt, off);
    __shared__ int lds_cnt;
    if (tid == 0) lds_cnt = 0;
    __syncthreads();
    if ((tid & 63) == 0) atomicAdd(&lds_cnt, cnt);
    __syncthreads();
    if (tid == 0) counts[m] = lds_cnt;
}

// Generic fallback (shape assumptions not met): per-element, correct-first.
__global__ __launch_bounds__(256) void nbr_kernel_generic(
    const float* __restrict__ data,
    const float* __restrict__ queries,
    const float* __restrict__ radius_p,
    float* __restrict__ out,
    int* __restrict__ counts,
    int N, long long mask_off, long long w_off)
{
    const int m = blockIdx.x;
    const int tid = threadIdx.x;
    const float r = radius_p[0];
    const float r2 = __fmul_rn(r, r);
    const float q0 = queries[3 * m + 0], q1 = queries[3 * m + 1], q2 = queries[3 * m + 2];
    const float sq_q = __fadd_rn(
        __fadd_rn(__fmul_rn(q0, q0), __fmul_rn(q1, q1)), __fmul_rn(q2, q2));
    float* mask_row = out + mask_off + (long long)m * N;
    float* w_row    = out + w_off    + (long long)m * N;
    int cnt = 0;
    for (int n = tid; n < N; n += 256) {
        const float d0 = data[3 * n], d1 = data[3 * n + 1], d2e = data[3 * n + 2];
        const float sq_d = __fadd_rn(
            __fadd_rn(__fmul_rn(d0, d0), __fmul_rn(d1, d1)), __fmul_rn(d2e, d2e));
        const float dot = __fmaf_rn(q2, d2e, __fmaf_rn(q1, d1, __fmul_rn(q0, d0)));
        float v = __fmaf_rn(-2.0f, dot, __fadd_rn(sq_q, sq_d));
        v = fmaxf(v, 0.0f);
        const bool in = (v <= r2);
        mask_row[n] = in ? 1.0f : 0.0f;
        w_row[n] = in ? v : 0.0f;
        cnt += in ? 1 : 0;
    }
    for (int off = 32; off > 0; off >>= 1) cnt += __shfl_down(cnt, off);
    __shared__ int lds_cnt;
    if (tid == 0) lds_cnt = 0;
    __syncthreads();
    if ((tid & 63) == 0) atomicAdd(&lds_cnt, cnt);
    __syncthreads();
    if (tid == 0) counts[m] = lds_cnt;
}

// Single-block exclusive scan of counts[M] -> row_splits[M+1] (as floats).
__global__ __launch_bounds__(256) void scan_kernel(
    const int* __restrict__ counts, float* __restrict__ out, int M)
{
    __shared__ int sums[256];
    const int t = threadIdx.x;
    const int CH = (M + 255) / 256;  // 48 for M=12288
    const int base = t * CH;

    int local[64];  // CH <= 64 assumed
    int s = 0;
    for (int i = 0; i < CH; ++i) {
        const int v = (base + i < M) ? counts[base + i] : 0;
        local[i] = v;
        s += v;
    }
    sums[t] = s;
    __syncthreads();
    for (int off = 1; off < 256; off <<= 1) {
        const int v = (t >= off) ? sums[t - off] : 0;
        __syncthreads();
        sums[t] += v;
        __syncthreads();
    }
    int prefix = sums[t] - s;  // exclusive prefix of this thread's chunk
    for (int i = 0; i < CH; ++i) {
        if (base + i < M) out[base + i] = (float)prefix;
        prefix += local[i];
    }
    if (t == 255) out[M] = (float)prefix;  // total
}

extern "C" void kernel_launch(void* const* d_in, const int* in_sizes, int n_in,
                              void* d_out, int out_size, void* d_ws, size_t ws_size,
                              hipStream_t stream) {
    const float* data    = (const float*)d_in[0];
    const float* queries = (const float*)d_in[1];
    const float* radius  = (const float*)d_in[2];

    const int N = in_sizes[0] / 3;  // 12288
    const int M = in_sizes[1] / 3;  // 12288

    float* out = (float*)d_out;
    int* counts = (int*)d_ws;

    const long long mask_off = (long long)M + 1;
    const long long w_off = mask_off + (long long)M * N;

    // Fast path needs: rows tile-divisible and flat row base == 1 (mod 16).
    const bool fast = (N % TILE == 0) && (M % 16 == 0) && (N % 16 == 0);
    if (fast) {
        nbr_kernel<<<M, 256, 0, stream>>>(data, queries, radius, out, counts,
                                          N, mask_off, w_off);
    } else {
        nbr_kernel_generic<<<M, 256, 0, stream>>>(data, queries, radius, out,
                                                  counts, N, mask_off, w_off);
    }
    scan_kernel<<<1, 256, 0, stream>>>(counts, out, M);
}